// Round 8
// baseline (404.029 us; speedup 1.0000x reference)
//
#include <hip/hip_runtime.h>
#include <cstdint>
#include <cstddef>

#define T_SEQ 4096
#define BATCH 2
#define HIDDEN 1024
#define NHEAD 8
#define DKV 128
#define BT (BATCH * T_SEQ)   // 8192
#define NCH 64               // chunks per batch
#define CHUNK_L 64
#define QSCALE 0.08838834764831845f
#define SCALE_P 1024.0f
#define SCALE_O 8192.0f
#define OEPS 0.7071067811865476f

typedef _Float16 half8 __attribute__((ext_vector_type(8)));
typedef float floatx4 __attribute__((ext_vector_type(4)));

union HBits { _Float16 h; unsigned short u; };

// ---------------------------------------------------------------------------
// fp32 -> fp16 cast, 8 elements/thread
// ---------------------------------------------------------------------------
__global__ void cast_f32_f16(const float* __restrict__ X, _Float16* __restrict__ Y, int n8)
{
    int idx = blockIdx.x * 256 + threadIdx.x;
    if (idx < n8) {
        float4 a = ((const float4*)X)[idx * 2];
        float4 b = ((const float4*)X)[idx * 2 + 1];
        half8 h = { (_Float16)a.x, (_Float16)a.y, (_Float16)a.z, (_Float16)a.w,
                    (_Float16)b.x, (_Float16)b.y, (_Float16)b.z, (_Float16)b.w };
        *(half8*)&Y[idx * 8] = h;
    }
}

__global__ void cast4_f32_f16(const float* __restrict__ A, const float* __restrict__ B,
                              const float* __restrict__ C, const float* __restrict__ D,
                              _Float16* __restrict__ a, _Float16* __restrict__ b,
                              _Float16* __restrict__ c, _Float16* __restrict__ d, int n8)
{
    int sel = blockIdx.y;
    const float* src = (sel == 0) ? A : (sel == 1) ? B : (sel == 2) ? C : D;
    _Float16* dst = (sel == 0) ? a : (sel == 1) ? b : (sel == 2) ? c : d;
    int idx = blockIdx.x * 256 + threadIdx.x;
    if (idx < n8) {
        float4 u = ((const float4*)src)[idx * 2];
        float4 v = ((const float4*)src)[idx * 2 + 1];
        half8 h = { (_Float16)u.x, (_Float16)u.y, (_Float16)u.z, (_Float16)u.w,
                    (_Float16)v.x, (_Float16)v.y, (_Float16)v.z, (_Float16)v.w };
        *(half8*)&dst[idx * 8] = h;
    }
}

// ---------------------------------------------------------------------------
// GEMM (NT) fp16 MFMA, fp16 out: C16[M,N] = A16[M,K] * W16[N,K]^T
// 128x128 tile, BK=32, 4 waves (2x2), 64x64/wave.
// A staged via global_load_lds; B fragments loaded DIRECT from global
// (L2-resident weights) to halve LDS-port pressure — LDS was the saturated
// resource at 606 TF (MfmaUtil 26%).
// ---------------------------------------------------------------------------
__global__ __launch_bounds__(256) void gemm_nt_f16_h16(const _Float16* __restrict__ A,
                                                       const _Float16* __restrict__ W,
                                                       _Float16* __restrict__ C,
                                                       int M, int N, int K)
{
    __shared__ _Float16 As[128 * 32];
    const int bm = blockIdx.y * 128;
    const int bn = blockIdx.x * 128;
    const int tid = threadIdx.x;
    const int w = tid >> 6;
    const int l = tid & 63;
    const int wm = (w >> 1) * 64;
    const int wn = (w & 1) * 64;
    const int lane16 = l & 15;
    const int quad = l >> 4;
    const int srow = w * 16 + (l >> 2);
    const int skh = (l & 3) * 8;

    const _Float16* Wb = W + (size_t)(bn + wn + lane16) * K + quad * 8;

    floatx4 acc[4][4];
#pragma unroll
    for (int i = 0; i < 4; ++i)
#pragma unroll
        for (int j = 0; j < 4; ++j)
            acc[i][j] = (floatx4){0.f, 0.f, 0.f, 0.f};

    for (int k0 = 0; k0 < K; k0 += 32) {
        // B fragments direct from global (issue first, latency hidden by waves)
        half8 b[4];
#pragma unroll
        for (int j = 0; j < 4; ++j)
            b[j] = *(const half8*)&Wb[(size_t)(j * 16) * K + k0];
        // A tile staged to LDS
#pragma unroll
        for (int c = 0; c < 2; ++c) {
            int row = c * 64 + srow;
            const _Float16* ga = A + (size_t)(bm + row) * K + k0 + skh;
            __builtin_amdgcn_global_load_lds(
                (const __attribute__((address_space(1))) void*)ga,
                (__attribute__((address_space(3))) void*)(As + c * 2048 + w * 512), 16, 0, 0);
        }
        __syncthreads();

        half8 a[4];
#pragma unroll
        for (int i = 0; i < 4; ++i)
            a[i] = *(const half8*)&As[(wm + i * 16 + lane16) * 32 + quad * 8];
#pragma unroll
        for (int i = 0; i < 4; ++i)
#pragma unroll
            for (int j = 0; j < 4; ++j)
                acc[i][j] = __builtin_amdgcn_mfma_f32_16x16x32_f16(a[i], b[j], acc[i][j], 0, 0, 0);
        __syncthreads();
    }
#pragma unroll
    for (int i = 0; i < 4; ++i)
#pragma unroll
        for (int j = 0; j < 4; ++j)
#pragma unroll
            for (int r = 0; r < 4; ++r)
                C[(size_t)(bm + wm + i * 16 + quad * 4 + r) * N + bn + wn + j * 16 + lane16] =
                    (_Float16)acc[i][j][r];
}

// ---------------------------------------------------------------------------
// Same structure, fp32 out with scale (final projection; undoes SCALE_O).
// ---------------------------------------------------------------------------
__global__ __launch_bounds__(256) void gemm_nt_f16_f32(const _Float16* __restrict__ A,
                                                       const _Float16* __restrict__ W,
                                                       float* __restrict__ C,
                                                       int M, int N, int K, float scale)
{
    __shared__ _Float16 As[128 * 32];
    const int bm = blockIdx.y * 128;
    const int bn = blockIdx.x * 128;
    const int tid = threadIdx.x;
    const int w = tid >> 6;
    const int l = tid & 63;
    const int wm = (w >> 1) * 64;
    const int wn = (w & 1) * 64;
    const int lane16 = l & 15;
    const int quad = l >> 4;
    const int srow = w * 16 + (l >> 2);
    const int skh = (l & 3) * 8;

    const _Float16* Wb = W + (size_t)(bn + wn + lane16) * K + quad * 8;

    floatx4 acc[4][4];
#pragma unroll
    for (int i = 0; i < 4; ++i)
#pragma unroll
        for (int j = 0; j < 4; ++j)
            acc[i][j] = (floatx4){0.f, 0.f, 0.f, 0.f};

    for (int k0 = 0; k0 < K; k0 += 32) {
        half8 b[4];
#pragma unroll
        for (int j = 0; j < 4; ++j)
            b[j] = *(const half8*)&Wb[(size_t)(j * 16) * K + k0];
#pragma unroll
        for (int c = 0; c < 2; ++c) {
            int row = c * 64 + srow;
            const _Float16* ga = A + (size_t)(bm + row) * K + k0 + skh;
            __builtin_amdgcn_global_load_lds(
                (const __attribute__((address_space(1))) void*)ga,
                (__attribute__((address_space(3))) void*)(As + c * 2048 + w * 512), 16, 0, 0);
        }
        __syncthreads();

        half8 a[4];
#pragma unroll
        for (int i = 0; i < 4; ++i)
            a[i] = *(const half8*)&As[(wm + i * 16 + lane16) * 32 + quad * 8];
#pragma unroll
        for (int i = 0; i < 4; ++i)
#pragma unroll
            for (int j = 0; j < 4; ++j)
                acc[i][j] = __builtin_amdgcn_mfma_f32_16x16x32_f16(a[i], b[j], acc[i][j], 0, 0, 0);
        __syncthreads();
    }
#pragma unroll
    for (int i = 0; i < 4; ++i)
#pragma unroll
        for (int j = 0; j < 4; ++j)
#pragma unroll
            for (int r = 0; r < 4; ++r)
                C[(size_t)(bm + wm + i * 16 + quad * 4 + r) * N + bn + wn + j * 16 + lane16] =
                    acc[i][j][r] * scale;
}

// ---------------------------------------------------------------------------
// Causal depthwise conv (K=4) + SiLU, column-walking, fused q/k.
// ---------------------------------------------------------------------------
#define CSTRIPE 16
__global__ __launch_bounds__(256) void conv_silu_col2(const _Float16* __restrict__ X, int ldx,
                                                      const float* __restrict__ Wq,
                                                      const float* __restrict__ Wk,
                                                      _Float16* __restrict__ Yq,
                                                      _Float16* __restrict__ Yk)
{
    const int sel = blockIdx.y;
    const _Float16* Xs = X + sel * HIDDEN;
    const float* Wc = sel ? Wk : Wq;
    _Float16* Y = sel ? Yk : Yq;

    int gid = blockIdx.x * 256 + threadIdx.x;
    int c = gid & 127;
    int sg = gid >> 7;
    int r0 = sg * CSTRIPE;
    int tloc = r0 & (T_SEQ - 1);
    int d0 = c * 8;

    float w0[8], w1[8], w2[8], w3[8];
#pragma unroll
    for (int e = 0; e < 8; ++e) {
        float4 wv = *(const float4*)&Wc[(d0 + e) * 4];
        w0[e] = wv.x; w1[e] = wv.y; w2[e] = wv.z; w3[e] = wv.w;
    }

    half8 xm1 = {0,0,0,0,0,0,0,0}, xm2 = xm1, xm3 = xm1;
    if (tloc >= 1) xm1 = *(const half8*)&Xs[(size_t)(r0 - 1) * ldx + d0];
    if (tloc >= 2) xm2 = *(const half8*)&Xs[(size_t)(r0 - 2) * ldx + d0];
    if (tloc >= 3) xm3 = *(const half8*)&Xs[(size_t)(r0 - 3) * ldx + d0];

    for (int i = 0; i < CSTRIPE; ++i) {
        half8 x0 = *(const half8*)&Xs[(size_t)(r0 + i) * ldx + d0];
        half8 o;
#pragma unroll
        for (int e = 0; e < 8; ++e) {
            float acc = fmaf((float)x0[e], w3[e],
                        fmaf((float)xm1[e], w2[e],
                        fmaf((float)xm2[e], w1[e], (float)xm3[e] * w0[e])));
            o[e] = (_Float16)(acc / (1.f + __expf(-acc)));
        }
        *(half8*)&Y[(size_t)(r0 + i) * HIDDEN + d0] = o;
        xm3 = xm2; xm2 = xm1; xm1 = x0;
    }
}

// ---------------------------------------------------------------------------
// Conv + SiLU for V, writing TRANSPOSED: vT[b*1024 + d][t]  (fp16).
// ---------------------------------------------------------------------------
__global__ __launch_bounds__(256) void conv_silu_T(const _Float16* __restrict__ X, int ldx,
                                                   const float* __restrict__ Wc,
                                                   _Float16* __restrict__ VT)
{
    __shared__ _Float16 xs[67 * 64];
    const int t0 = blockIdx.x * 64;
    const int dt = blockIdx.y * 64;
    const int z = blockIdx.z;
    const int tid = threadIdx.x;

#pragma unroll
    for (int i = 0; i < 3; ++i) {
        int p = tid + 256 * i;
        if (p < 536) {
            int row = p >> 3, d8 = (p & 7) * 8;
            int t = t0 - 3 + row;
            half8 v;
            if (t >= 0)
                v = *(const half8*)&X[((size_t)z * T_SEQ + t) * ldx + dt + d8];
            else
                v = (half8){0, 0, 0, 0, 0, 0, 0, 0};
            *(half8*)&xs[row * 64 + d8] = v;
        }
    }
    __syncthreads();

    const int d = tid & 63;
    const int dg = dt + d;
    float4 w = *(const float4*)&Wc[dg * 4];
#pragma unroll
    for (int u = 0; u < 2; ++u) {
        int tg = (tid >> 6) + u * 4;
        half8 o;
#pragma unroll
        for (int s = 0; s < 8; ++s) {
            int base = (tg * 8 + s + 3) * 64 + d;
            float acc = (float)xs[base] * w.w
                      + (float)xs[base - 64] * w.z
                      + (float)xs[base - 128] * w.y
                      + (float)xs[base - 192] * w.x;
            o[s] = (_Float16)(acc / (1.f + __expf(-acc)));
        }
        *(half8*)&VT[((size_t)z * HIDDEN + dg) * T_SEQ + t0 + tg * 8] = o;
    }
}

// ---------------------------------------------------------------------------
// Feature map, MFMA, fused q/k via blockIdx.z.
// ---------------------------------------------------------------------------
__global__ __launch_bounds__(256) void fm_mfma2(const _Float16* __restrict__ Xq,
                                                const _Float16* __restrict__ Xk,
                                                const _Float16* __restrict__ Wfm,  // 4x16384
                                                const float* __restrict__ Bq1,
                                                const float* __restrict__ Bq2,
                                                const float* __restrict__ Bk1,
                                                const float* __restrict__ Bk2,
                                                _Float16* __restrict__ OUTq,
                                                _Float16* __restrict__ OUTk)
{
    const int sel = blockIdx.z;
    const _Float16* X = sel ? Xk : Xq;
    const _Float16* W1h = Wfm + (sel ? 2 * 16384 : 0);
    const _Float16* W2h = Wfm + (sel ? 3 * 16384 : 16384);
    const float* B1 = sel ? Bk1 : Bq1;
    const float* B2 = sel ? Bk2 : Bq2;
    _Float16* OUT = sel ? OUTk : OUTq;

    __shared__ _Float16 xs[4 * 64 * 32];   // [kstep][row][32]
    const int t0 = blockIdx.x * 64;
    const int h = blockIdx.y;
    const int tid = threadIdx.x;
    const int w = tid >> 6;
    const int l = tid & 63;
    const int lane16 = l & 15;
    const int quad = l >> 4;

#pragma unroll
    for (int c = 0; c < 4; ++c) {
        int row = c * 16 + (l >> 2);
        const _Float16* g = X + (size_t)(t0 + row) * HIDDEN + h * DKV + w * 32 + (l & 3) * 8;
        __builtin_amdgcn_global_load_lds(
            (const __attribute__((address_space(1))) void*)g,
            (__attribute__((address_space(3))) void*)(xs + w * 2048 + c * 512), 16, 0, 0);
    }
    __syncthreads();

    floatx4 acc1[4][2], acc2[4][2];
#pragma unroll
    for (int i = 0; i < 4; ++i)
#pragma unroll
        for (int j = 0; j < 2; ++j) {
            acc1[i][j] = (floatx4){0.f, 0.f, 0.f, 0.f};
            acc2[i][j] = (floatx4){0.f, 0.f, 0.f, 0.f};
        }

#pragma unroll
    for (int s = 0; s < 4; ++s) {
        half8 a[4];
#pragma unroll
        for (int mt = 0; mt < 4; ++mt)
            a[mt] = *(const half8*)&xs[s * 2048 + (mt * 16 + lane16) * 32 + quad * 8];
#pragma unroll
        for (int nt = 0; nt < 2; ++nt) {
            int e = w * 32 + nt * 16 + lane16;
            half8 b1 = *(const half8*)&W1h[(size_t)e * DKV + s * 32 + quad * 8];
            half8 b2 = *(const half8*)&W2h[(size_t)e * DKV + s * 32 + quad * 8];
#pragma unroll
            for (int mt = 0; mt < 4; ++mt) {
                acc1[mt][nt] = __builtin_amdgcn_mfma_f32_16x16x32_f16(a[mt], b1, acc1[mt][nt], 0, 0, 0);
                acc2[mt][nt] = __builtin_amdgcn_mfma_f32_16x16x32_f16(a[mt], b2, acc2[mt][nt], 0, 0, 0);
            }
        }
    }

#pragma unroll
    for (int nt = 0; nt < 2; ++nt) {
        int e = w * 32 + nt * 16 + lane16;
        float b1v = B1[e], b2v = B2[e];
#pragma unroll
        for (int mt = 0; mt < 4; ++mt)
#pragma unroll
            for (int r = 0; r < 4; ++r) {
                float o = (acc1[mt][nt][r] + b1v) * (acc2[mt][nt][r] + b2v);
                OUT[(size_t)(t0 + mt * 16 + quad * 4 + r) * HIDDEN + h * DKV + e] = (_Float16)o;
            }
    }
}

// ---------------------------------------------------------------------------
// Per-chunk S^T[dv][dk] = sum_j V[j][dv] K[j][dk], MFMA.
// ---------------------------------------------------------------------------
__global__ __launch_bounds__(256) void ktv_mfma(const _Float16* __restrict__ Kf,
                                                const _Float16* __restrict__ VT,
                                                float* __restrict__ G)
{
    __shared__ _Float16 kt[128 * 72];
    const int c = blockIdx.x;
    const int bh = blockIdx.y;
    const int b = bh >> 3, h = bh & 7;
    const int tid = threadIdx.x;
    const int w = tid >> 6;
    const int l = tid & 63;
    const int lane16 = l & 15;
    const int quad = l >> 4;
    const size_t rowbase = (size_t)b * T_SEQ + (size_t)c * CHUNK_L;

    {
        const int dk0 = (tid >> 4) * 8;
        const int jb = (tid & 15) * 4;
        half8 r0 = *(const half8*)&Kf[(rowbase + jb + 0) * HIDDEN + h * DKV + dk0];
        half8 r1 = *(const half8*)&Kf[(rowbase + jb + 1) * HIDDEN + h * DKV + dk0];
        half8 r2 = *(const half8*)&Kf[(rowbase + jb + 2) * HIDDEN + h * DKV + dk0];
        half8 r3 = *(const half8*)&Kf[(rowbase + jb + 3) * HIDDEN + h * DKV + dk0];
#pragma unroll
        for (int dk = 0; dk < 8; ++dk) {
            HBits a0, a1, a2, a3;
            a0.h = r0[dk]; a1.h = r1[dk]; a2.h = r2[dk]; a3.h = r3[dk];
            unsigned int lo = ((unsigned int)a1.u << 16) | a0.u;
            unsigned int hi = ((unsigned int)a3.u << 16) | a2.u;
            *(unsigned int*)&kt[(dk0 + dk) * 72 + jb] = lo;
            *(unsigned int*)&kt[(dk0 + dk) * 72 + jb + 2] = hi;
        }
    }
    __syncthreads();

    const int m0 = (w >> 1) * 64;
    const int n0 = (w & 1) * 64;
    floatx4 acc[4][4];
#pragma unroll
    for (int i = 0; i < 4; ++i)
#pragma unroll
        for (int j = 0; j < 4; ++j)
            acc[i][j] = (floatx4){0.f, 0.f, 0.f, 0.f};

#pragma unroll
    for (int s = 0; s < 2; ++s) {
        half8 a[4], bb[4];
#pragma unroll
        for (int mt = 0; mt < 4; ++mt) {
            int dv = m0 + mt * 16 + lane16;
            a[mt] = *(const half8*)&VT[((size_t)bh * DKV + dv) * T_SEQ + c * CHUNK_L + s * 32 + quad * 8];
        }
#pragma unroll
        for (int nt = 0; nt < 4; ++nt)
            bb[nt] = *(const half8*)&kt[(n0 + nt * 16 + lane16) * 72 + s * 32 + quad * 8];
#pragma unroll
        for (int mt = 0; mt < 4; ++mt)
#pragma unroll
            for (int nt = 0; nt < 4; ++nt)
                acc[mt][nt] = __builtin_amdgcn_mfma_f32_16x16x32_f16(a[mt], bb[nt], acc[mt][nt], 0, 0, 0);
    }

    float* Gp = G + ((size_t)bh * NCH + c) * (DKV * DKV);
#pragma unroll
    for (int mt = 0; mt < 4; ++mt)
#pragma unroll
        for (int nt = 0; nt < 4; ++nt)
#pragma unroll
            for (int r = 0; r < 4; ++r)
                Gp[(size_t)(m0 + mt * 16 + quad * 4 + r) * DKV + n0 + nt * 16 + lane16] =
                    acc[mt][nt][r];
}

// ---------------------------------------------------------------------------
// Exclusive prefix over chunks; G fp32 in -> Gh fp16 out (scaled by SCALE_P).
// ---------------------------------------------------------------------------
__global__ void prefix_kernel(const float* __restrict__ G, _Float16* __restrict__ Gh)
{
    int idx = blockIdx.x * 256 + threadIdx.x;   // 16 * 16384
    int bh = idx >> 14;
    int e = idx & 16383;
    const float* p = G + (size_t)bh * NCH * 16384 + e;
    _Float16* q = Gh + (size_t)bh * NCH * 16384 + e;
    float run = 0.f;
#pragma unroll
    for (int c = 0; c < NCH; ++c) {
        q[(size_t)c * 16384] = (_Float16)(run * SCALE_P);
        run += p[(size_t)c * 16384];
    }
}

// ---------------------------------------------------------------------------
// Attention per chunk, MFMA.
// ---------------------------------------------------------------------------
#define PSLD 40
__global__ __launch_bounds__(256) void attn_mfma(const _Float16* __restrict__ Qf,
                                                 const _Float16* __restrict__ Kf,
                                                 const _Float16* __restrict__ VT,
                                                 const _Float16* __restrict__ Gh,
                                                 _Float16* __restrict__ O)
{
    __shared__ _Float16 ps[2 * 64 * PSLD];
    const int c = blockIdx.x;
    const int bh = blockIdx.y;
    const int b = bh >> 3, h = bh & 7;
    const int tid = threadIdx.x;
    const int w = tid >> 6;
    const int l = tid & 63;
    const int lane16 = l & 15;
    const int quad = l >> 4;
    const size_t rowbase = (size_t)b * T_SEQ + (size_t)c * CHUNK_L;

    {
        const int m0 = (w >> 1) * 32;
        const int n0 = (w & 1) * 32;
        floatx4 aq[2][2];
#pragma unroll
        for (int i = 0; i < 2; ++i)
#pragma unroll
            for (int j = 0; j < 2; ++j)
                aq[i][j] = (floatx4){0.f, 0.f, 0.f, 0.f};
#pragma unroll
        for (int s = 0; s < 4; ++s) {
            half8 a[2], bb[2];
#pragma unroll
            for (int mt = 0; mt < 2; ++mt)
                a[mt] = *(const half8*)&Qf[(rowbase + m0 + mt * 16 + lane16) * HIDDEN +
                                           h * DKV + s * 32 + quad * 8];
#pragma unroll
            for (int nt = 0; nt < 2; ++nt)
                bb[nt] = *(const half8*)&Kf[(rowbase + n0 + nt * 16 + lane16) * HIDDEN +
                                            h * DKV + s * 32 + quad * 8];
#pragma unroll
            for (int mt = 0; mt < 2; ++mt)
#pragma unroll
                for (int nt = 0; nt < 2; ++nt)
                    aq[mt][nt] = __builtin_amdgcn_mfma_f32_16x16x32_f16(a[mt], bb[nt], aq[mt][nt], 0, 0, 0);
        }
#pragma unroll
        for (int mt = 0; mt < 2; ++mt)
#pragma unroll
            for (int nt = 0; nt < 2; ++nt) {
                int j = n0 + nt * 16 + lane16;
#pragma unroll
                for (int r = 0; r < 4; ++r) {
                    int i = m0 + mt * 16 + quad * 4 + r;
                    float v = (j <= i) ? aq[mt][nt][r] * SCALE_P : 0.f;
                    ps[(j >> 5) * 64 * PSLD + i * PSLD + (j & 31)] = (_Float16)v;
                }
            }
    }
    __syncthreads();

    const int n0o = w * 32;
    floatx4 accO[4][2];
#pragma unroll
    for (int i = 0; i < 4; ++i)
#pragma unroll
        for (int j = 0; j < 2; ++j)
            accO[i][j] = (floatx4){0.f, 0.f, 0.f, 0.f};

#pragma unroll
    for (int s = 0; s < 2; ++s) {
        half8 a[4], bb[2];
#pragma unroll
        for (int mt = 0; mt < 4; ++mt)
            a[mt] = *(const half8*)&ps[s * 64 * PSLD + (mt * 16 + lane16) * PSLD + quad * 8];
#pragma unroll
        for (int nt = 0; nt < 2; ++nt) {
            int dv = n0o + nt * 16 + lane16;
            bb[nt] = *(const half8*)&VT[((size_t)bh * DKV + dv) * T_SEQ + c * CHUNK_L + s * 32 + quad * 8];
        }
#pragma unroll
        for (int mt = 0; mt < 4; ++mt)
#pragma unroll
            for (int nt = 0; nt < 2; ++nt)
                accO[mt][nt] = __builtin_amdgcn_mfma_f32_16x16x32_f16(a[mt], bb[nt], accO[mt][nt], 0, 0, 0);
    }

    const _Float16* gh = Gh + ((size_t)bh * NCH + c) * (DKV * DKV);
#pragma unroll
    for (int s = 0; s < 4; ++s) {
        half8 a[4], bb[2];
#pragma unroll
        for (int mt = 0; mt < 4; ++mt)
            a[mt] = *(const half8*)&Qf[(rowbase + mt * 16 + lane16) * HIDDEN +
                                       h * DKV + s * 32 + quad * 8];
#pragma unroll
        for (int nt = 0; nt < 2; ++nt) {
            int dv = n0o + nt * 16 + lane16;
            bb[nt] = *(const half8*)&gh[(size_t)dv * DKV + s * 32 + quad * 8];
        }
#pragma unroll
        for (int mt = 0; mt < 4; ++mt)
#pragma unroll
            for (int nt = 0; nt < 2; ++nt)
                accO[mt][nt] = __builtin_amdgcn_mfma_f32_16x16x32_f16(a[mt], bb[nt], accO[mt][nt], 0, 0, 0);
    }

#pragma unroll
    for (int mt = 0; mt < 4; ++mt)
#pragma unroll
        for (int nt = 0; nt < 2; ++nt)
#pragma unroll
            for (int r = 0; r < 4; ++r)
                O[(rowbase + mt * 16 + quad * 4 + r) * HIDDEN + h * DKV + n0o + nt * 16 + lane16] =
                    (_Float16)(accO[mt][nt][r] * OEPS);
}

// ---------------------------------------------------------------------------
// Workspace map (192 MiB, phase-aliased) — unchanged from R4.
// ---------------------------------------------------------------------------
extern "C" void kernel_launch(void* const* d_in, const int* in_sizes, int n_in,
                              void* d_out, int out_size, void* d_ws, size_t ws_size,
                              hipStream_t stream)
{
    (void)in_sizes; (void)n_in; (void)out_size; (void)ws_size;
    const float* hs = (const float*)d_in[0];
    const float* wq = (const float*)d_in[1];
    const float* wk = (const float*)d_in[2];
    const float* wv = (const float*)d_in[3];
    const float* wo = (const float*)d_in[4];
    const float* cq = (const float*)d_in[5];
    const float* ck = (const float*)d_in[6];
    const float* cv = (const float*)d_in[7];
    const float* fmq_w1 = (const float*)d_in[8];
    const float* fmq_b1 = (const float*)d_in[9];
    const float* fmq_w2 = (const float*)d_in[10];
    const float* fmq_b2 = (const float*)d_in[11];
    const float* fmk_w1 = (const float*)d_in[12];
    const float* fmk_b1 = (const float*)d_in[13];
    const float* fmk_w2 = (const float*)d_in[14];
    const float* fmk_b2 = (const float*)d_in[15];
    float* out = (float*)d_out;
    char* ws = (char*)d_ws;

    const size_t MB = 1024 * 1024;
    _Float16* h16     = (_Float16*)(ws + 0);
    _Float16* wqkv16  = (_Float16*)(ws + 16 * MB);         // 3072x1024
    _Float16* wo16    = wqkv16 + (3 << 20);
    _Float16* fmw     = wqkv16 + (4 << 20);                // 4 x 16384
    _Float16* qkvlin  = (_Float16*)(ws + 32 * MB);         // [8192][3072]
    _Float16* qf16    = (_Float16*)(ws + 32 * MB);
    _Float16* kf16    = (_Float16*)(ws + 48 * MB);
    _Float16* Gh      = (_Float16*)(ws + 64 * MB);         // 32 MB
    _Float16* qc16    = (_Float16*)(ws + 80 * MB);
    _Float16* kc16    = (_Float16*)(ws + 96 * MB);
    _Float16* O16     = (_Float16*)(ws + 96 * MB);
    _Float16* vT      = (_Float16*)(ws + 112 * MB);
    float*    G       = (float*)(ws + 128 * MB);           // 64 MB

    // ---- P0: casts ----
    cast_f32_f16<<<4096, 256, 0, stream>>>(hs, h16, BT * HIDDEN / 8);
    cast4_f32_f16<<<dim3(512, 4), 256, 0, stream>>>(wq, wk, wv, wo,
                                                    wqkv16, wqkv16 + (1 << 20), wqkv16 + (2 << 20), wo16,
                                                    HIDDEN * HIDDEN / 8);
    cast4_f32_f16<<<dim3(8, 4), 256, 0, stream>>>(fmq_w1, fmq_w2, fmk_w1, fmk_w2,
                                                  fmw, fmw + 16384, fmw + 2 * 16384, fmw + 3 * 16384,
                                                  DKV * DKV / 8);

    // ---- P1: fused QKV projection (N = 3072), 128x128 tiles ----
    dim3 gqkv(3 * HIDDEN / 128, BT / 128);   // (24, 64) = 1536 blocks
    gemm_nt_f16_h16<<<gqkv, 256, 0, stream>>>(h16, wqkv16, qkvlin, BT, 3 * HIDDEN, HIDDEN);

    // ---- P2: conv + silu (q,k fused; v transposed) ----
    conv_silu_col2<<<dim3((128 * (BT / CSTRIPE)) / 256, 2), 256, 0, stream>>>(
        qkvlin, 3 * HIDDEN, cq, ck, qc16, kc16);
    dim3 cg(T_SEQ / 64, HIDDEN / 64, BATCH);
    conv_silu_T<<<cg, 256, 0, stream>>>(qkvlin + 2 * HIDDEN, 3 * HIDDEN, cv, vT);

    // ---- P3: feature maps (q,k fused) ----
    dim3 fg(BT / 64, NHEAD, 2);
    fm_mfma2<<<fg, 256, 0, stream>>>(qc16, kc16, fmw, fmq_b1, fmq_b2, fmk_b1, fmk_b2, qf16, kf16);

    // ---- P4-P6: chunked linear attention ----
    dim3 ag(NCH, BATCH * NHEAD);
    ktv_mfma<<<ag, 256, 0, stream>>>(kf16, vT, G);
    prefix_kernel<<<(16 * 16384) / 256, 256, 0, stream>>>(G, Gh);
    attn_mfma<<<ag, 256, 0, stream>>>(qf16, kf16, vT, Gh, O16);

    // ---- P7: output projection (undo SCALE_O) ----
    dim3 gg(HIDDEN / 128, BT / 128);
    gemm_nt_f16_f32<<<gg, 256, 0, stream>>>(O16, wo16, out, BT, HIDDEN, HIDDEN, 1.0f / SCALE_O);
}

// Round 9
// 335.203 us; speedup vs baseline: 1.2053x; 1.2053x over previous
//
#include <hip/hip_runtime.h>
#include <cstdint>
#include <cstddef>

#define T_SEQ 4096
#define BATCH 2
#define HIDDEN 1024
#define NHEAD 8
#define DKV 128
#define BT (BATCH * T_SEQ)   // 8192
#define NCH 64               // chunks per batch
#define CHUNK_L 64
#define QSCALE 0.08838834764831845f
#define SCALE_P 1024.0f
#define SCALE_O 8192.0f
#define OEPS 0.7071067811865476f

typedef _Float16 half8 __attribute__((ext_vector_type(8)));
typedef float floatx4 __attribute__((ext_vector_type(4)));

union HBits { _Float16 h; unsigned short u; };

// ---------------------------------------------------------------------------
// fp32 -> fp16 cast, 8 elements/thread
// ---------------------------------------------------------------------------
__global__ void cast_f32_f16(const float* __restrict__ X, _Float16* __restrict__ Y, int n8)
{
    int idx = blockIdx.x * 256 + threadIdx.x;
    if (idx < n8) {
        float4 a = ((const float4*)X)[idx * 2];
        float4 b = ((const float4*)X)[idx * 2 + 1];
        half8 h = { (_Float16)a.x, (_Float16)a.y, (_Float16)a.z, (_Float16)a.w,
                    (_Float16)b.x, (_Float16)b.y, (_Float16)b.z, (_Float16)b.w };
        *(half8*)&Y[idx * 8] = h;
    }
}

__global__ void cast4_f32_f16(const float* __restrict__ A, const float* __restrict__ B,
                              const float* __restrict__ C, const float* __restrict__ D,
                              _Float16* __restrict__ a, _Float16* __restrict__ b,
                              _Float16* __restrict__ c, _Float16* __restrict__ d, int n8)
{
    int sel = blockIdx.y;
    const float* src = (sel == 0) ? A : (sel == 1) ? B : (sel == 2) ? C : D;
    _Float16* dst = (sel == 0) ? a : (sel == 1) ? b : (sel == 2) ? c : d;
    int idx = blockIdx.x * 256 + threadIdx.x;
    if (idx < n8) {
        float4 u = ((const float4*)src)[idx * 2];
        float4 v = ((const float4*)src)[idx * 2 + 1];
        half8 h = { (_Float16)u.x, (_Float16)u.y, (_Float16)u.z, (_Float16)u.w,
                    (_Float16)v.x, (_Float16)v.y, (_Float16)v.z, (_Float16)v.w };
        *(half8*)&dst[idx * 8] = h;
    }
}

// ---------------------------------------------------------------------------
// GEMM (NT) fp16 MFMA, fp16 out: C16[M,N] = A16[M,K] * W16[N,K]^T
// 128x128 tile, BK=64 (halves barrier-drain count vs BK=32), 4 waves (2x2),
// 64x64/wave. A and B staged via global_load_lds width=16. Rows are 128 B so
// columns are XOR-swizzled by row&7 (applied on the GLOBAL source column to
// keep global_load_lds lane-contiguity; readers XOR their quad column).
// K-accumulation order identical to BK=32 version -> bit-identical C.
// ---------------------------------------------------------------------------
__global__ __launch_bounds__(256) void gemm_nt_f16_h16(const _Float16* __restrict__ A,
                                                       const _Float16* __restrict__ W,
                                                       _Float16* __restrict__ C,
                                                       int M, int N, int K)
{
    __shared__ _Float16 As[128 * 64];
    __shared__ _Float16 Ws[128 * 64];
    const int bm = blockIdx.y * 128;
    const int bn = blockIdx.x * 128;
    const int tid = threadIdx.x;
    const int w = tid >> 6;
    const int l = tid & 63;
    const int wm = (w >> 1) * 64;
    const int wn = (w & 1) * 64;
    const int lane16 = l & 15;
    const int quad = l >> 4;
    const int srow = w * 8 + (l >> 3);              // + c*32
    const int skh = ((l & 7) ^ (l >> 3)) * 8;       // swizzled global column (halfs)
    const int rsw = lane16 & 7;                     // row&7 for fragment reads

    floatx4 acc[4][4];
#pragma unroll
    for (int i = 0; i < 4; ++i)
#pragma unroll
        for (int j = 0; j < 4; ++j)
            acc[i][j] = (floatx4){0.f, 0.f, 0.f, 0.f};

    for (int k0 = 0; k0 < K; k0 += 64) {
#pragma unroll
        for (int c = 0; c < 4; ++c) {
            int row = c * 32 + srow;
            const _Float16* ga = A + (size_t)(bm + row) * K + k0 + skh;
            const _Float16* gw = W + (size_t)(bn + row) * K + k0 + skh;
            __builtin_amdgcn_global_load_lds(
                (const __attribute__((address_space(1))) void*)ga,
                (__attribute__((address_space(3))) void*)(As + c * 2048 + w * 512), 16, 0, 0);
            __builtin_amdgcn_global_load_lds(
                (const __attribute__((address_space(1))) void*)gw,
                (__attribute__((address_space(3))) void*)(Ws + c * 2048 + w * 512), 16, 0, 0);
        }
        __syncthreads();

#pragma unroll
        for (int s = 0; s < 2; ++s) {
            const int pc = (((s * 4 + quad) ^ rsw)) * 8;   // physical column (halfs)
            half8 a[4], b[4];
#pragma unroll
            for (int i = 0; i < 4; ++i) {
                a[i] = *(const half8*)&As[(wm + i * 16 + lane16) * 64 + pc];
                b[i] = *(const half8*)&Ws[(wn + i * 16 + lane16) * 64 + pc];
            }
#pragma unroll
            for (int i = 0; i < 4; ++i)
#pragma unroll
                for (int j = 0; j < 4; ++j)
                    acc[i][j] = __builtin_amdgcn_mfma_f32_16x16x32_f16(a[i], b[j], acc[i][j], 0, 0, 0);
        }
        __syncthreads();
    }
#pragma unroll
    for (int i = 0; i < 4; ++i)
#pragma unroll
        for (int j = 0; j < 4; ++j)
#pragma unroll
            for (int r = 0; r < 4; ++r)
                C[(size_t)(bm + wm + i * 16 + quad * 4 + r) * N + bn + wn + j * 16 + lane16] =
                    (_Float16)acc[i][j][r];
}

// ---------------------------------------------------------------------------
// Same BK=64 structure, fp32 out with scale (final projection; undoes SCALE_O).
// ---------------------------------------------------------------------------
__global__ __launch_bounds__(256) void gemm_nt_f16_f32(const _Float16* __restrict__ A,
                                                       const _Float16* __restrict__ W,
                                                       float* __restrict__ C,
                                                       int M, int N, int K, float scale)
{
    __shared__ _Float16 As[128 * 64];
    __shared__ _Float16 Ws[128 * 64];
    const int bm = blockIdx.y * 128;
    const int bn = blockIdx.x * 128;
    const int tid = threadIdx.x;
    const int w = tid >> 6;
    const int l = tid & 63;
    const int wm = (w >> 1) * 64;
    const int wn = (w & 1) * 64;
    const int lane16 = l & 15;
    const int quad = l >> 4;
    const int srow = w * 8 + (l >> 3);
    const int skh = ((l & 7) ^ (l >> 3)) * 8;
    const int rsw = lane16 & 7;

    floatx4 acc[4][4];
#pragma unroll
    for (int i = 0; i < 4; ++i)
#pragma unroll
        for (int j = 0; j < 4; ++j)
            acc[i][j] = (floatx4){0.f, 0.f, 0.f, 0.f};

    for (int k0 = 0; k0 < K; k0 += 64) {
#pragma unroll
        for (int c = 0; c < 4; ++c) {
            int row = c * 32 + srow;
            const _Float16* ga = A + (size_t)(bm + row) * K + k0 + skh;
            const _Float16* gw = W + (size_t)(bn + row) * K + k0 + skh;
            __builtin_amdgcn_global_load_lds(
                (const __attribute__((address_space(1))) void*)ga,
                (__attribute__((address_space(3))) void*)(As + c * 2048 + w * 512), 16, 0, 0);
            __builtin_amdgcn_global_load_lds(
                (const __attribute__((address_space(1))) void*)gw,
                (__attribute__((address_space(3))) void*)(Ws + c * 2048 + w * 512), 16, 0, 0);
        }
        __syncthreads();

#pragma unroll
        for (int s = 0; s < 2; ++s) {
            const int pc = (((s * 4 + quad) ^ rsw)) * 8;
            half8 a[4], b[4];
#pragma unroll
            for (int i = 0; i < 4; ++i) {
                a[i] = *(const half8*)&As[(wm + i * 16 + lane16) * 64 + pc];
                b[i] = *(const half8*)&Ws[(wn + i * 16 + lane16) * 64 + pc];
            }
#pragma unroll
            for (int i = 0; i < 4; ++i)
#pragma unroll
                for (int j = 0; j < 4; ++j)
                    acc[i][j] = __builtin_amdgcn_mfma_f32_16x16x32_f16(a[i], b[j], acc[i][j], 0, 0, 0);
        }
        __syncthreads();
    }
#pragma unroll
    for (int i = 0; i < 4; ++i)
#pragma unroll
        for (int j = 0; j < 4; ++j)
#pragma unroll
            for (int r = 0; r < 4; ++r)
                C[(size_t)(bm + wm + i * 16 + quad * 4 + r) * N + bn + wn + j * 16 + lane16] =
                    acc[i][j][r] * scale;
}

// ---------------------------------------------------------------------------
// Causal depthwise conv (K=4) + SiLU, column-walking, fused q/k.
// ---------------------------------------------------------------------------
#define CSTRIPE 16
__global__ __launch_bounds__(256) void conv_silu_col2(const _Float16* __restrict__ X, int ldx,
                                                      const float* __restrict__ Wq,
                                                      const float* __restrict__ Wk,
                                                      _Float16* __restrict__ Yq,
                                                      _Float16* __restrict__ Yk)
{
    const int sel = blockIdx.y;
    const _Float16* Xs = X + sel * HIDDEN;
    const float* Wc = sel ? Wk : Wq;
    _Float16* Y = sel ? Yk : Yq;

    int gid = blockIdx.x * 256 + threadIdx.x;
    int c = gid & 127;
    int sg = gid >> 7;
    int r0 = sg * CSTRIPE;
    int tloc = r0 & (T_SEQ - 1);
    int d0 = c * 8;

    float w0[8], w1[8], w2[8], w3[8];
#pragma unroll
    for (int e = 0; e < 8; ++e) {
        float4 wv = *(const float4*)&Wc[(d0 + e) * 4];
        w0[e] = wv.x; w1[e] = wv.y; w2[e] = wv.z; w3[e] = wv.w;
    }

    half8 xm1 = {0,0,0,0,0,0,0,0}, xm2 = xm1, xm3 = xm1;
    if (tloc >= 1) xm1 = *(const half8*)&Xs[(size_t)(r0 - 1) * ldx + d0];
    if (tloc >= 2) xm2 = *(const half8*)&Xs[(size_t)(r0 - 2) * ldx + d0];
    if (tloc >= 3) xm3 = *(const half8*)&Xs[(size_t)(r0 - 3) * ldx + d0];

    for (int i = 0; i < CSTRIPE; ++i) {
        half8 x0 = *(const half8*)&Xs[(size_t)(r0 + i) * ldx + d0];
        half8 o;
#pragma unroll
        for (int e = 0; e < 8; ++e) {
            float acc = fmaf((float)x0[e], w3[e],
                        fmaf((float)xm1[e], w2[e],
                        fmaf((float)xm2[e], w1[e], (float)xm3[e] * w0[e])));
            o[e] = (_Float16)(acc / (1.f + __expf(-acc)));
        }
        *(half8*)&Y[(size_t)(r0 + i) * HIDDEN + d0] = o;
        xm3 = xm2; xm2 = xm1; xm1 = x0;
    }
}

// ---------------------------------------------------------------------------
// Conv + SiLU for V, writing TRANSPOSED: vT[b*1024 + d][t]  (fp16).
// ---------------------------------------------------------------------------
__global__ __launch_bounds__(256) void conv_silu_T(const _Float16* __restrict__ X, int ldx,
                                                   const float* __restrict__ Wc,
                                                   _Float16* __restrict__ VT)
{
    __shared__ _Float16 xs[67 * 64];
    const int t0 = blockIdx.x * 64;
    const int dt = blockIdx.y * 64;
    const int z = blockIdx.z;
    const int tid = threadIdx.x;

#pragma unroll
    for (int i = 0; i < 3; ++i) {
        int p = tid + 256 * i;
        if (p < 536) {
            int row = p >> 3, d8 = (p & 7) * 8;
            int t = t0 - 3 + row;
            half8 v;
            if (t >= 0)
                v = *(const half8*)&X[((size_t)z * T_SEQ + t) * ldx + dt + d8];
            else
                v = (half8){0, 0, 0, 0, 0, 0, 0, 0};
            *(half8*)&xs[row * 64 + d8] = v;
        }
    }
    __syncthreads();

    const int d = tid & 63;
    const int dg = dt + d;
    float4 w = *(const float4*)&Wc[dg * 4];
#pragma unroll
    for (int u = 0; u < 2; ++u) {
        int tg = (tid >> 6) + u * 4;
        half8 o;
#pragma unroll
        for (int s = 0; s < 8; ++s) {
            int base = (tg * 8 + s + 3) * 64 + d;
            float acc = (float)xs[base] * w.w
                      + (float)xs[base - 64] * w.z
                      + (float)xs[base - 128] * w.y
                      + (float)xs[base - 192] * w.x;
            o[s] = (_Float16)(acc / (1.f + __expf(-acc)));
        }
        *(half8*)&VT[((size_t)z * HIDDEN + dg) * T_SEQ + t0 + tg * 8] = o;
    }
}

// ---------------------------------------------------------------------------
// Feature map, MFMA, fused q/k via blockIdx.z.
// ---------------------------------------------------------------------------
__global__ __launch_bounds__(256) void fm_mfma2(const _Float16* __restrict__ Xq,
                                                const _Float16* __restrict__ Xk,
                                                const _Float16* __restrict__ Wfm,  // 4x16384
                                                const float* __restrict__ Bq1,
                                                const float* __restrict__ Bq2,
                                                const float* __restrict__ Bk1,
                                                const float* __restrict__ Bk2,
                                                _Float16* __restrict__ OUTq,
                                                _Float16* __restrict__ OUTk)
{
    const int sel = blockIdx.z;
    const _Float16* X = sel ? Xk : Xq;
    const _Float16* W1h = Wfm + (sel ? 2 * 16384 : 0);
    const _Float16* W2h = Wfm + (sel ? 3 * 16384 : 16384);
    const float* B1 = sel ? Bk1 : Bq1;
    const float* B2 = sel ? Bk2 : Bq2;
    _Float16* OUT = sel ? OUTk : OUTq;

    __shared__ _Float16 xs[4 * 64 * 32];   // [kstep][row][32]
    const int t0 = blockIdx.x * 64;
    const int h = blockIdx.y;
    const int tid = threadIdx.x;
    const int w = tid >> 6;
    const int l = tid & 63;
    const int lane16 = l & 15;
    const int quad = l >> 4;

#pragma unroll
    for (int c = 0; c < 4; ++c) {
        int row = c * 16 + (l >> 2);
        const _Float16* g = X + (size_t)(t0 + row) * HIDDEN + h * DKV + w * 32 + (l & 3) * 8;
        __builtin_amdgcn_global_load_lds(
            (const __attribute__((address_space(1))) void*)g,
            (__attribute__((address_space(3))) void*)(xs + w * 2048 + c * 512), 16, 0, 0);
    }
    __syncthreads();

    floatx4 acc1[4][2], acc2[4][2];
#pragma unroll
    for (int i = 0; i < 4; ++i)
#pragma unroll
        for (int j = 0; j < 2; ++j) {
            acc1[i][j] = (floatx4){0.f, 0.f, 0.f, 0.f};
            acc2[i][j] = (floatx4){0.f, 0.f, 0.f, 0.f};
        }

#pragma unroll
    for (int s = 0; s < 4; ++s) {
        half8 a[4];
#pragma unroll
        for (int mt = 0; mt < 4; ++mt)
            a[mt] = *(const half8*)&xs[s * 2048 + (mt * 16 + lane16) * 32 + quad * 8];
#pragma unroll
        for (int nt = 0; nt < 2; ++nt) {
            int e = w * 32 + nt * 16 + lane16;
            half8 b1 = *(const half8*)&W1h[(size_t)e * DKV + s * 32 + quad * 8];
            half8 b2 = *(const half8*)&W2h[(size_t)e * DKV + s * 32 + quad * 8];
#pragma unroll
            for (int mt = 0; mt < 4; ++mt) {
                acc1[mt][nt] = __builtin_amdgcn_mfma_f32_16x16x32_f16(a[mt], b1, acc1[mt][nt], 0, 0, 0);
                acc2[mt][nt] = __builtin_amdgcn_mfma_f32_16x16x32_f16(a[mt], b2, acc2[mt][nt], 0, 0, 0);
            }
        }
    }

#pragma unroll
    for (int nt = 0; nt < 2; ++nt) {
        int e = w * 32 + nt * 16 + lane16;
        float b1v = B1[e], b2v = B2[e];
#pragma unroll
        for (int mt = 0; mt < 4; ++mt)
#pragma unroll
            for (int r = 0; r < 4; ++r) {
                float o = (acc1[mt][nt][r] + b1v) * (acc2[mt][nt][r] + b2v);
                OUT[(size_t)(t0 + mt * 16 + quad * 4 + r) * HIDDEN + h * DKV + e] = (_Float16)o;
            }
    }
}

// ---------------------------------------------------------------------------
// Per-chunk S^T[dv][dk] = sum_j V[j][dv] K[j][dk], MFMA.
// ---------------------------------------------------------------------------
__global__ __launch_bounds__(256) void ktv_mfma(const _Float16* __restrict__ Kf,
                                                const _Float16* __restrict__ VT,
                                                float* __restrict__ G)
{
    __shared__ _Float16 kt[128 * 72];
    const int c = blockIdx.x;
    const int bh = blockIdx.y;
    const int b = bh >> 3, h = bh & 7;
    const int tid = threadIdx.x;
    const int w = tid >> 6;
    const int l = tid & 63;
    const int lane16 = l & 15;
    const int quad = l >> 4;
    const size_t rowbase = (size_t)b * T_SEQ + (size_t)c * CHUNK_L;

    {
        const int dk0 = (tid >> 4) * 8;
        const int jb = (tid & 15) * 4;
        half8 r0 = *(const half8*)&Kf[(rowbase + jb + 0) * HIDDEN + h * DKV + dk0];
        half8 r1 = *(const half8*)&Kf[(rowbase + jb + 1) * HIDDEN + h * DKV + dk0];
        half8 r2 = *(const half8*)&Kf[(rowbase + jb + 2) * HIDDEN + h * DKV + dk0];
        half8 r3 = *(const half8*)&Kf[(rowbase + jb + 3) * HIDDEN + h * DKV + dk0];
#pragma unroll
        for (int dk = 0; dk < 8; ++dk) {
            HBits a0, a1, a2, a3;
            a0.h = r0[dk]; a1.h = r1[dk]; a2.h = r2[dk]; a3.h = r3[dk];
            unsigned int lo = ((unsigned int)a1.u << 16) | a0.u;
            unsigned int hi = ((unsigned int)a3.u << 16) | a2.u;
            *(unsigned int*)&kt[(dk0 + dk) * 72 + jb] = lo;
            *(unsigned int*)&kt[(dk0 + dk) * 72 + jb + 2] = hi;
        }
    }
    __syncthreads();

    const int m0 = (w >> 1) * 64;
    const int n0 = (w & 1) * 64;
    floatx4 acc[4][4];
#pragma unroll
    for (int i = 0; i < 4; ++i)
#pragma unroll
        for (int j = 0; j < 4; ++j)
            acc[i][j] = (floatx4){0.f, 0.f, 0.f, 0.f};

#pragma unroll
    for (int s = 0; s < 2; ++s) {
        half8 a[4], bb[4];
#pragma unroll
        for (int mt = 0; mt < 4; ++mt) {
            int dv = m0 + mt * 16 + lane16;
            a[mt] = *(const half8*)&VT[((size_t)bh * DKV + dv) * T_SEQ + c * CHUNK_L + s * 32 + quad * 8];
        }
#pragma unroll
        for (int nt = 0; nt < 4; ++nt)
            bb[nt] = *(const half8*)&kt[(n0 + nt * 16 + lane16) * 72 + s * 32 + quad * 8];
#pragma unroll
        for (int mt = 0; mt < 4; ++mt)
#pragma unroll
            for (int nt = 0; nt < 4; ++nt)
                acc[mt][nt] = __builtin_amdgcn_mfma_f32_16x16x32_f16(a[mt], bb[nt], acc[mt][nt], 0, 0, 0);
    }

    float* Gp = G + ((size_t)bh * NCH + c) * (DKV * DKV);
#pragma unroll
    for (int mt = 0; mt < 4; ++mt)
#pragma unroll
        for (int nt = 0; nt < 4; ++nt)
#pragma unroll
            for (int r = 0; r < 4; ++r)
                Gp[(size_t)(m0 + mt * 16 + quad * 4 + r) * DKV + n0 + nt * 16 + lane16] =
                    acc[mt][nt][r];
}

// ---------------------------------------------------------------------------
// Exclusive prefix over chunks; G fp32 in -> Gh fp16 out (scaled by SCALE_P).
// ---------------------------------------------------------------------------
__global__ void prefix_kernel(const float* __restrict__ G, _Float16* __restrict__ Gh)
{
    int idx = blockIdx.x * 256 + threadIdx.x;   // 16 * 16384
    int bh = idx >> 14;
    int e = idx & 16383;
    const float* p = G + (size_t)bh * NCH * 16384 + e;
    _Float16* q = Gh + (size_t)bh * NCH * 16384 + e;
    float run = 0.f;
#pragma unroll
    for (int c = 0; c < NCH; ++c) {
        q[(size_t)c * 16384] = (_Float16)(run * SCALE_P);
        run += p[(size_t)c * 16384];
    }
}

// ---------------------------------------------------------------------------
// Attention per chunk, MFMA.
// ---------------------------------------------------------------------------
#define PSLD 40
__global__ __launch_bounds__(256) void attn_mfma(const _Float16* __restrict__ Qf,
                                                 const _Float16* __restrict__ Kf,
                                                 const _Float16* __restrict__ VT,
                                                 const _Float16* __restrict__ Gh,
                                                 _Float16* __restrict__ O)
{
    __shared__ _Float16 ps[2 * 64 * PSLD];
    const int c = blockIdx.x;
    const int bh = blockIdx.y;
    const int b = bh >> 3, h = bh & 7;
    const int tid = threadIdx.x;
    const int w = tid >> 6;
    const int l = tid & 63;
    const int lane16 = l & 15;
    const int quad = l >> 4;
    const size_t rowbase = (size_t)b * T_SEQ + (size_t)c * CHUNK_L;

    {
        const int m0 = (w >> 1) * 32;
        const int n0 = (w & 1) * 32;
        floatx4 aq[2][2];
#pragma unroll
        for (int i = 0; i < 2; ++i)
#pragma unroll
            for (int j = 0; j < 2; ++j)
                aq[i][j] = (floatx4){0.f, 0.f, 0.f, 0.f};
#pragma unroll
        for (int s = 0; s < 4; ++s) {
            half8 a[2], bb[2];
#pragma unroll
            for (int mt = 0; mt < 2; ++mt)
                a[mt] = *(const half8*)&Qf[(rowbase + m0 + mt * 16 + lane16) * HIDDEN +
                                           h * DKV + s * 32 + quad * 8];
#pragma unroll
            for (int nt = 0; nt < 2; ++nt)
                bb[nt] = *(const half8*)&Kf[(rowbase + n0 + nt * 16 + lane16) * HIDDEN +
                                            h * DKV + s * 32 + quad * 8];
#pragma unroll
            for (int mt = 0; mt < 2; ++mt)
#pragma unroll
                for (int nt = 0; nt < 2; ++nt)
                    aq[mt][nt] = __builtin_amdgcn_mfma_f32_16x16x32_f16(a[mt], bb[nt], aq[mt][nt], 0, 0, 0);
        }
#pragma unroll
        for (int mt = 0; mt < 2; ++mt)
#pragma unroll
            for (int nt = 0; nt < 2; ++nt) {
                int j = n0 + nt * 16 + lane16;
#pragma unroll
                for (int r = 0; r < 4; ++r) {
                    int i = m0 + mt * 16 + quad * 4 + r;
                    float v = (j <= i) ? aq[mt][nt][r] * SCALE_P : 0.f;
                    ps[(j >> 5) * 64 * PSLD + i * PSLD + (j & 31)] = (_Float16)v;
                }
            }
    }
    __syncthreads();

    const int n0o = w * 32;
    floatx4 accO[4][2];
#pragma unroll
    for (int i = 0; i < 4; ++i)
#pragma unroll
        for (int j = 0; j < 2; ++j)
            accO[i][j] = (floatx4){0.f, 0.f, 0.f, 0.f};

#pragma unroll
    for (int s = 0; s < 2; ++s) {
        half8 a[4], bb[2];
#pragma unroll
        for (int mt = 0; mt < 4; ++mt)
            a[mt] = *(const half8*)&ps[s * 64 * PSLD + (mt * 16 + lane16) * PSLD + quad * 8];
#pragma unroll
        for (int nt = 0; nt < 2; ++nt) {
            int dv = n0o + nt * 16 + lane16;
            bb[nt] = *(const half8*)&VT[((size_t)bh * DKV + dv) * T_SEQ + c * CHUNK_L + s * 32 + quad * 8];
        }
#pragma unroll
        for (int mt = 0; mt < 4; ++mt)
#pragma unroll
            for (int nt = 0; nt < 2; ++nt)
                accO[mt][nt] = __builtin_amdgcn_mfma_f32_16x16x32_f16(a[mt], bb[nt], accO[mt][nt], 0, 0, 0);
    }

    const _Float16* gh = Gh + ((size_t)bh * NCH + c) * (DKV * DKV);
#pragma unroll
    for (int s = 0; s < 4; ++s) {
        half8 a[4], bb[2];
#pragma unroll
        for (int mt = 0; mt < 4; ++mt)
            a[mt] = *(const half8*)&Qf[(rowbase + mt * 16 + lane16) * HIDDEN +
                                       h * DKV + s * 32 + quad * 8];
#pragma unroll
        for (int nt = 0; nt < 2; ++nt) {
            int dv = n0o + nt * 16 + lane16;
            bb[nt] = *(const half8*)&gh[(size_t)dv * DKV + s * 32 + quad * 8];
        }
#pragma unroll
        for (int mt = 0; mt < 4; ++mt)
#pragma unroll
            for (int nt = 0; nt < 2; ++nt)
                accO[mt][nt] = __builtin_amdgcn_mfma_f32_16x16x32_f16(a[mt], bb[nt], accO[mt][nt], 0, 0, 0);
    }

#pragma unroll
    for (int mt = 0; mt < 4; ++mt)
#pragma unroll
        for (int nt = 0; nt < 2; ++nt)
#pragma unroll
            for (int r = 0; r < 4; ++r)
                O[(rowbase + mt * 16 + quad * 4 + r) * HIDDEN + h * DKV + n0o + nt * 16 + lane16] =
                    (_Float16)(accO[mt][nt][r] * OEPS);
}

// ---------------------------------------------------------------------------
// Workspace map (192 MiB, phase-aliased) — unchanged from R4.
// ---------------------------------------------------------------------------
extern "C" void kernel_launch(void* const* d_in, const int* in_sizes, int n_in,
                              void* d_out, int out_size, void* d_ws, size_t ws_size,
                              hipStream_t stream)
{
    (void)in_sizes; (void)n_in; (void)out_size; (void)ws_size;
    const float* hs = (const float*)d_in[0];
    const float* wq = (const float*)d_in[1];
    const float* wk = (const float*)d_in[2];
    const float* wv = (const float*)d_in[3];
    const float* wo = (const float*)d_in[4];
    const float* cq = (const float*)d_in[5];
    const float* ck = (const float*)d_in[6];
    const float* cv = (const float*)d_in[7];
    const float* fmq_w1 = (const float*)d_in[8];
    const float* fmq_b1 = (const float*)d_in[9];
    const float* fmq_w2 = (const float*)d_in[10];
    const float* fmq_b2 = (const float*)d_in[11];
    const float* fmk_w1 = (const float*)d_in[12];
    const float* fmk_b1 = (const float*)d_in[13];
    const float* fmk_w2 = (const float*)d_in[14];
    const float* fmk_b2 = (const float*)d_in[15];
    float* out = (float*)d_out;
    char* ws = (char*)d_ws;

    const size_t MB = 1024 * 1024;
    _Float16* h16     = (_Float16*)(ws + 0);
    _Float16* wqkv16  = (_Float16*)(ws + 16 * MB);         // 3072x1024
    _Float16* wo16    = wqkv16 + (3 << 20);
    _Float16* fmw     = wqkv16 + (4 << 20);                // 4 x 16384
    _Float16* qkvlin  = (_Float16*)(ws + 32 * MB);         // [8192][3072]
    _Float16* qf16    = (_Float16*)(ws + 32 * MB);
    _Float16* kf16    = (_Float16*)(ws + 48 * MB);
    _Float16* Gh      = (_Float16*)(ws + 64 * MB);         // 32 MB
    _Float16* qc16    = (_Float16*)(ws + 80 * MB);
    _Float16* kc16    = (_Float16*)(ws + 96 * MB);
    _Float16* O16     = (_Float16*)(ws + 96 * MB);
    _Float16* vT      = (_Float16*)(ws + 112 * MB);
    float*    G       = (float*)(ws + 128 * MB);           // 64 MB

    // ---- P0: casts ----
    cast_f32_f16<<<4096, 256, 0, stream>>>(hs, h16, BT * HIDDEN / 8);
    cast4_f32_f16<<<dim3(512, 4), 256, 0, stream>>>(wq, wk, wv, wo,
                                                    wqkv16, wqkv16 + (1 << 20), wqkv16 + (2 << 20), wo16,
                                                    HIDDEN * HIDDEN / 8);
    cast4_f32_f16<<<dim3(8, 4), 256, 0, stream>>>(fmq_w1, fmq_w2, fmk_w1, fmk_w2,
                                                  fmw, fmw + 16384, fmw + 2 * 16384, fmw + 3 * 16384,
                                                  DKV * DKV / 8);

    // ---- P1: fused QKV projection (N = 3072), 128x128 tiles, BK=64 ----
    dim3 gqkv(3 * HIDDEN / 128, BT / 128);   // (24, 64) = 1536 blocks
    gemm_nt_f16_h16<<<gqkv, 256, 0, stream>>>(h16, wqkv16, qkvlin, BT, 3 * HIDDEN, HIDDEN);

    // ---- P2: conv + silu (q,k fused; v transposed) ----
    conv_silu_col2<<<dim3((128 * (BT / CSTRIPE)) / 256, 2), 256, 0, stream>>>(
        qkvlin, 3 * HIDDEN, cq, ck, qc16, kc16);
    dim3 cg(T_SEQ / 64, HIDDEN / 64, BATCH);
    conv_silu_T<<<cg, 256, 0, stream>>>(qkvlin + 2 * HIDDEN, 3 * HIDDEN, cv, vT);

    // ---- P3: feature maps (q,k fused) ----
    dim3 fg(BT / 64, NHEAD, 2);
    fm_mfma2<<<fg, 256, 0, stream>>>(qc16, kc16, fmw, fmq_b1, fmq_b2, fmk_b1, fmk_b2, qf16, kf16);

    // ---- P4-P6: chunked linear attention ----
    dim3 ag(NCH, BATCH * NHEAD);
    ktv_mfma<<<ag, 256, 0, stream>>>(kf16, vT, G);
    prefix_kernel<<<(16 * 16384) / 256, 256, 0, stream>>>(G, Gh);
    attn_mfma<<<ag, 256, 0, stream>>>(qf16, kf16, vT, Gh, O16);

    // ---- P7: output projection (undo SCALE_O), BK=64 ----
    dim3 gg(HIDDEN / 128, BT / 128);
    gemm_nt_f16_f32<<<gg, 256, 0, stream>>>(O16, wo16, out, BT, HIDDEN, HIDDEN, 1.0f / SCALE_O);
}

// Round 11
// 327.054 us; speedup vs baseline: 1.2354x; 1.0249x over previous
//
#include <hip/hip_runtime.h>
#include <cstdint>
#include <cstddef>

#define T_SEQ 4096
#define BATCH 2
#define HIDDEN 1024
#define NHEAD 8
#define DKV 128
#define BT (BATCH * T_SEQ)   // 8192
#define NCH 64               // chunks per batch
#define CHUNK_L 64
#define QSCALE 0.08838834764831845f
#define SCALE_P 1024.0f
#define SCALE_O 8192.0f
#define OEPS 0.7071067811865476f

typedef _Float16 half8 __attribute__((ext_vector_type(8)));
typedef float floatx4 __attribute__((ext_vector_type(4)));

union HBits { _Float16 h; unsigned short u; };

// ---------------------------------------------------------------------------
// fp32 -> fp16 cast, 8 elements/thread
// ---------------------------------------------------------------------------
__global__ void cast_f32_f16(const float* __restrict__ X, _Float16* __restrict__ Y, int n8)
{
    int idx = blockIdx.x * 256 + threadIdx.x;
    if (idx < n8) {
        float4 a = ((const float4*)X)[idx * 2];
        float4 b = ((const float4*)X)[idx * 2 + 1];
        half8 h = { (_Float16)a.x, (_Float16)a.y, (_Float16)a.z, (_Float16)a.w,
                    (_Float16)b.x, (_Float16)b.y, (_Float16)b.z, (_Float16)b.w };
        *(half8*)&Y[idx * 8] = h;
    }
}

// 8 weight tensors in one launch; blockIdx.y selects. Oversized grid blocks
// for the small fm tensors exit immediately.
__global__ void cast8_f32_f16(const float* __restrict__ s0, const float* __restrict__ s1,
                              const float* __restrict__ s2, const float* __restrict__ s3,
                              const float* __restrict__ s4, const float* __restrict__ s5,
                              const float* __restrict__ s6, const float* __restrict__ s7,
                              _Float16* __restrict__ d0, _Float16* __restrict__ d1,
                              _Float16* __restrict__ d2, _Float16* __restrict__ d3,
                              _Float16* __restrict__ d4, _Float16* __restrict__ d5,
                              _Float16* __restrict__ d6, _Float16* __restrict__ d7,
                              int nbig, int nsmall)
{
    int sel = blockIdx.y;
    const float* src; _Float16* dst; int n8;
    switch (sel) {
        case 0: src = s0; dst = d0; n8 = nbig; break;
        case 1: src = s1; dst = d1; n8 = nbig; break;
        case 2: src = s2; dst = d2; n8 = nbig; break;
        case 3: src = s3; dst = d3; n8 = nbig; break;
        case 4: src = s4; dst = d4; n8 = nsmall; break;
        case 5: src = s5; dst = d5; n8 = nsmall; break;
        case 6: src = s6; dst = d6; n8 = nsmall; break;
        default: src = s7; dst = d7; n8 = nsmall; break;
    }
    int idx = blockIdx.x * 256 + threadIdx.x;
    if (idx < n8) {
        float4 u = ((const float4*)src)[idx * 2];
        float4 v = ((const float4*)src)[idx * 2 + 1];
        half8 h = { (_Float16)u.x, (_Float16)u.y, (_Float16)u.z, (_Float16)u.w,
                    (_Float16)v.x, (_Float16)v.y, (_Float16)v.z, (_Float16)v.w };
        *(half8*)&dst[idx * 8] = h;
    }
}

// ---------------------------------------------------------------------------
// GEMM (NT) fp16 MFMA, fp16 out: 128x128 tile, BK=64, 4 waves, XOR-swizzled
// LDS columns (swizzle applied on global source column so global_load_lds
// stays lane-contiguous). Proven R8 structure: 747 TF, 0 bank conflicts.
// ---------------------------------------------------------------------------
__global__ __launch_bounds__(256) void gemm_nt_f16_h16(const _Float16* __restrict__ A,
                                                       const _Float16* __restrict__ W,
                                                       _Float16* __restrict__ C,
                                                       int M, int N, int K)
{
    __shared__ _Float16 As[128 * 64];
    __shared__ _Float16 Ws[128 * 64];
    const int bm = blockIdx.y * 128;
    const int bn = blockIdx.x * 128;
    const int tid = threadIdx.x;
    const int w = tid >> 6;
    const int l = tid & 63;
    const int wm = (w >> 1) * 64;
    const int wn = (w & 1) * 64;
    const int lane16 = l & 15;
    const int quad = l >> 4;
    const int srow = w * 8 + (l >> 3);
    const int skh = ((l & 7) ^ (l >> 3)) * 8;
    const int rsw = lane16 & 7;

    floatx4 acc[4][4];
#pragma unroll
    for (int i = 0; i < 4; ++i)
#pragma unroll
        for (int j = 0; j < 4; ++j)
            acc[i][j] = (floatx4){0.f, 0.f, 0.f, 0.f};

    for (int k0 = 0; k0 < K; k0 += 64) {
#pragma unroll
        for (int c = 0; c < 4; ++c) {
            int row = c * 32 + srow;
            const _Float16* ga = A + (size_t)(bm + row) * K + k0 + skh;
            const _Float16* gw = W + (size_t)(bn + row) * K + k0 + skh;
            __builtin_amdgcn_global_load_lds(
                (const __attribute__((address_space(1))) void*)ga,
                (__attribute__((address_space(3))) void*)(As + c * 2048 + w * 512), 16, 0, 0);
            __builtin_amdgcn_global_load_lds(
                (const __attribute__((address_space(1))) void*)gw,
                (__attribute__((address_space(3))) void*)(Ws + c * 2048 + w * 512), 16, 0, 0);
        }
        __syncthreads();

#pragma unroll
        for (int s = 0; s < 2; ++s) {
            const int pc = (((s * 4 + quad) ^ rsw)) * 8;
            half8 a[4], b[4];
#pragma unroll
            for (int i = 0; i < 4; ++i) {
                a[i] = *(const half8*)&As[(wm + i * 16 + lane16) * 64 + pc];
                b[i] = *(const half8*)&Ws[(wn + i * 16 + lane16) * 64 + pc];
            }
#pragma unroll
            for (int i = 0; i < 4; ++i)
#pragma unroll
                for (int j = 0; j < 4; ++j)
                    acc[i][j] = __builtin_amdgcn_mfma_f32_16x16x32_f16(a[i], b[j], acc[i][j], 0, 0, 0);
        }
        __syncthreads();
    }
#pragma unroll
    for (int i = 0; i < 4; ++i)
#pragma unroll
        for (int j = 0; j < 4; ++j)
#pragma unroll
            for (int r = 0; r < 4; ++r)
                C[(size_t)(bm + wm + i * 16 + quad * 4 + r) * N + bn + wn + j * 16 + lane16] =
                    (_Float16)acc[i][j][r];
}

// ---------------------------------------------------------------------------
// Same BK=64 structure, fp32 out with scale (final projection; undoes SCALE_O).
// ---------------------------------------------------------------------------
__global__ __launch_bounds__(256) void gemm_nt_f16_f32(const _Float16* __restrict__ A,
                                                       const _Float16* __restrict__ W,
                                                       float* __restrict__ C,
                                                       int M, int N, int K, float scale)
{
    __shared__ _Float16 As[128 * 64];
    __shared__ _Float16 Ws[128 * 64];
    const int bm = blockIdx.y * 128;
    const int bn = blockIdx.x * 128;
    const int tid = threadIdx.x;
    const int w = tid >> 6;
    const int l = tid & 63;
    const int wm = (w >> 1) * 64;
    const int wn = (w & 1) * 64;
    const int lane16 = l & 15;
    const int quad = l >> 4;
    const int srow = w * 8 + (l >> 3);
    const int skh = ((l & 7) ^ (l >> 3)) * 8;
    const int rsw = lane16 & 7;

    floatx4 acc[4][4];
#pragma unroll
    for (int i = 0; i < 4; ++i)
#pragma unroll
        for (int j = 0; j < 4; ++j)
            acc[i][j] = (floatx4){0.f, 0.f, 0.f, 0.f};

    for (int k0 = 0; k0 < K; k0 += 64) {
#pragma unroll
        for (int c = 0; c < 4; ++c) {
            int row = c * 32 + srow;
            const _Float16* ga = A + (size_t)(bm + row) * K + k0 + skh;
            const _Float16* gw = W + (size_t)(bn + row) * K + k0 + skh;
            __builtin_amdgcn_global_load_lds(
                (const __attribute__((address_space(1))) void*)ga,
                (__attribute__((address_space(3))) void*)(As + c * 2048 + w * 512), 16, 0, 0);
            __builtin_amdgcn_global_load_lds(
                (const __attribute__((address_space(1))) void*)gw,
                (__attribute__((address_space(3))) void*)(Ws + c * 2048 + w * 512), 16, 0, 0);
        }
        __syncthreads();

#pragma unroll
        for (int s = 0; s < 2; ++s) {
            const int pc = (((s * 4 + quad) ^ rsw)) * 8;
            half8 a[4], b[4];
#pragma unroll
            for (int i = 0; i < 4; ++i) {
                a[i] = *(const half8*)&As[(wm + i * 16 + lane16) * 64 + pc];
                b[i] = *(const half8*)&Ws[(wn + i * 16 + lane16) * 64 + pc];
            }
#pragma unroll
            for (int i = 0; i < 4; ++i)
#pragma unroll
                for (int j = 0; j < 4; ++j)
                    acc[i][j] = __builtin_amdgcn_mfma_f32_16x16x32_f16(a[i], b[j], acc[i][j], 0, 0, 0);
        }
        __syncthreads();
    }
#pragma unroll
    for (int i = 0; i < 4; ++i)
#pragma unroll
        for (int j = 0; j < 4; ++j)
#pragma unroll
            for (int r = 0; r < 4; ++r)
                C[(size_t)(bm + wm + i * 16 + quad * 4 + r) * N + bn + wn + j * 16 + lane16] =
                    acc[i][j][r] * scale;
}

// ---------------------------------------------------------------------------
// Fused conv+SiLU, all three streams in one launch:
//   blockIdx.y = 0/1 : q/k column-walking path (256 active blocks; rest exit)
//   blockIdx.y = 2   : v path with LDS transpose (all 2048 blocks)
// ---------------------------------------------------------------------------
#define CSTRIPE 16
__global__ __launch_bounds__(256) void conv_silu_all(const _Float16* __restrict__ X, int ldx,
                                                     const float* __restrict__ Wq,
                                                     const float* __restrict__ Wk,
                                                     const float* __restrict__ Wv,
                                                     _Float16* __restrict__ Yq,
                                                     _Float16* __restrict__ Yk,
                                                     _Float16* __restrict__ VT)
{
    const int path = blockIdx.y;
    const int tid = threadIdx.x;

    if (path < 2) {
        int gid = blockIdx.x * 256 + tid;
        if (gid >= 128 * (BT / CSTRIPE)) return;   // only 256 blocks active here

        const _Float16* Xs = X + path * HIDDEN;
        const float* Wc = path ? Wk : Wq;
        _Float16* Y = path ? Yk : Yq;

        int c = gid & 127;
        int sg = gid >> 7;
        int r0 = sg * CSTRIPE;
        int tloc = r0 & (T_SEQ - 1);
        int d0 = c * 8;

        float w0[8], w1[8], w2[8], w3[8];
#pragma unroll
        for (int e = 0; e < 8; ++e) {
            float4 wv = *(const float4*)&Wc[(d0 + e) * 4];
            w0[e] = wv.x; w1[e] = wv.y; w2[e] = wv.z; w3[e] = wv.w;
        }

        half8 xm1 = {0,0,0,0,0,0,0,0}, xm2 = xm1, xm3 = xm1;
        if (tloc >= 1) xm1 = *(const half8*)&Xs[(size_t)(r0 - 1) * ldx + d0];
        if (tloc >= 2) xm2 = *(const half8*)&Xs[(size_t)(r0 - 2) * ldx + d0];
        if (tloc >= 3) xm3 = *(const half8*)&Xs[(size_t)(r0 - 3) * ldx + d0];

        for (int i = 0; i < CSTRIPE; ++i) {
            half8 x0 = *(const half8*)&Xs[(size_t)(r0 + i) * ldx + d0];
            half8 o;
#pragma unroll
            for (int e = 0; e < 8; ++e) {
                float acc = fmaf((float)x0[e], w3[e],
                            fmaf((float)xm1[e], w2[e],
                            fmaf((float)xm2[e], w1[e], (float)xm3[e] * w0[e])));
                o[e] = (_Float16)(acc / (1.f + __expf(-acc)));
            }
            *(half8*)&Y[(size_t)(r0 + i) * HIDDEN + d0] = o;
            xm3 = xm2; xm2 = xm1; xm1 = x0;
        }
        return;
    }

    // ---- V path: LDS-staged transpose ----
    __shared__ _Float16 xs[67 * 64];
    const int bx = blockIdx.x;               // 2048 = 64 ttiles * 16 dtiles * 2 batch
    const int t0 = (bx & 63) * 64;
    const int dt = ((bx >> 6) & 15) * 64;
    const int z = bx >> 10;
    const _Float16* Xv = X + 2 * HIDDEN;

#pragma unroll
    for (int i = 0; i < 3; ++i) {
        int p = tid + 256 * i;
        if (p < 536) {
            int row = p >> 3, d8 = (p & 7) * 8;
            int t = t0 - 3 + row;
            half8 v;
            if (t >= 0)
                v = *(const half8*)&Xv[((size_t)z * T_SEQ + t) * ldx + dt + d8];
            else
                v = (half8){0, 0, 0, 0, 0, 0, 0, 0};
            *(half8*)&xs[row * 64 + d8] = v;
        }
    }
    __syncthreads();

    const int d = tid & 63;
    const int dg = dt + d;
    float4 w = *(const float4*)&Wv[dg * 4];
#pragma unroll
    for (int u = 0; u < 2; ++u) {
        int tg = (tid >> 6) + u * 4;
        half8 o;
#pragma unroll
        for (int s = 0; s < 8; ++s) {
            int base = (tg * 8 + s + 3) * 64 + d;
            float acc = (float)xs[base] * w.w
                      + (float)xs[base - 64] * w.z
                      + (float)xs[base - 128] * w.y
                      + (float)xs[base - 192] * w.x;
            o[s] = (_Float16)(acc / (1.f + __expf(-acc)));
        }
        *(half8*)&VT[((size_t)z * HIDDEN + dg) * T_SEQ + t0 + tg * 8] = o;
    }
}

// ---------------------------------------------------------------------------
// Feature map, MFMA, fused q/k via blockIdx.z.
// ---------------------------------------------------------------------------
__global__ __launch_bounds__(256) void fm_mfma2(const _Float16* __restrict__ Xq,
                                                const _Float16* __restrict__ Xk,
                                                const _Float16* __restrict__ Wfm,  // 4x16384
                                                const float* __restrict__ Bq1,
                                                const float* __restrict__ Bq2,
                                                const float* __restrict__ Bk1,
                                                const float* __restrict__ Bk2,
                                                _Float16* __restrict__ OUTq,
                                                _Float16* __restrict__ OUTk)
{
    const int sel = blockIdx.z;
    const _Float16* X = sel ? Xk : Xq;
    const _Float16* W1h = Wfm + (sel ? 2 * 16384 : 0);
    const _Float16* W2h = Wfm + (sel ? 3 * 16384 : 16384);
    const float* B1 = sel ? Bk1 : Bq1;
    const float* B2 = sel ? Bk2 : Bq2;
    _Float16* OUT = sel ? OUTk : OUTq;

    __shared__ _Float16 xs[4 * 64 * 32];   // [kstep][row][32]
    const int t0 = blockIdx.x * 64;
    const int h = blockIdx.y;
    const int tid = threadIdx.x;
    const int w = tid >> 6;
    const int l = tid & 63;
    const int lane16 = l & 15;
    const int quad = l >> 4;

#pragma unroll
    for (int c = 0; c < 4; ++c) {
        int row = c * 16 + (l >> 2);
        const _Float16* g = X + (size_t)(t0 + row) * HIDDEN + h * DKV + w * 32 + (l & 3) * 8;
        __builtin_amdgcn_global_load_lds(
            (const __attribute__((address_space(1))) void*)g,
            (__attribute__((address_space(3))) void*)(xs + w * 2048 + c * 512), 16, 0, 0);
    }
    __syncthreads();

    floatx4 acc1[4][2], acc2[4][2];
#pragma unroll
    for (int i = 0; i < 4; ++i)
#pragma unroll
        for (int j = 0; j < 2; ++j) {
            acc1[i][j] = (floatx4){0.f, 0.f, 0.f, 0.f};
            acc2[i][j] = (floatx4){0.f, 0.f, 0.f, 0.f};
        }

#pragma unroll
    for (int s = 0; s < 4; ++s) {
        half8 a[4];
#pragma unroll
        for (int mt = 0; mt < 4; ++mt)
            a[mt] = *(const half8*)&xs[s * 2048 + (mt * 16 + lane16) * 32 + quad * 8];
#pragma unroll
        for (int nt = 0; nt < 2; ++nt) {
            int e = w * 32 + nt * 16 + lane16;
            half8 b1 = *(const half8*)&W1h[(size_t)e * DKV + s * 32 + quad * 8];
            half8 b2 = *(const half8*)&W2h[(size_t)e * DKV + s * 32 + quad * 8];
#pragma unroll
            for (int mt = 0; mt < 4; ++mt) {
                acc1[mt][nt] = __builtin_amdgcn_mfma_f32_16x16x32_f16(a[mt], b1, acc1[mt][nt], 0, 0, 0);
                acc2[mt][nt] = __builtin_amdgcn_mfma_f32_16x16x32_f16(a[mt], b2, acc2[mt][nt], 0, 0, 0);
            }
        }
    }

#pragma unroll
    for (int nt = 0; nt < 2; ++nt) {
        int e = w * 32 + nt * 16 + lane16;
        float b1v = B1[e], b2v = B2[e];
#pragma unroll
        for (int mt = 0; mt < 4; ++mt)
#pragma unroll
            for (int r = 0; r < 4; ++r) {
                float o = (acc1[mt][nt][r] + b1v) * (acc2[mt][nt][r] + b2v);
                OUT[(size_t)(t0 + mt * 16 + quad * 4 + r) * HIDDEN + h * DKV + e] = (_Float16)o;
            }
    }
}

// ---------------------------------------------------------------------------
// Per-chunk S^T[dv][dk] = sum_j V[j][dv] K[j][dk], MFMA. Output fp16 (values
// O(1), fp16-normal; prefix accumulates the scan in fp32).
// ---------------------------------------------------------------------------
__global__ __launch_bounds__(256) void ktv_mfma(const _Float16* __restrict__ Kf,
                                                const _Float16* __restrict__ VT,
                                                _Float16* __restrict__ G16)
{
    __shared__ _Float16 kt[128 * 72];
    const int c = blockIdx.x;
    const int bh = blockIdx.y;
    const int b = bh >> 3, h = bh & 7;
    const int tid = threadIdx.x;
    const int w = tid >> 6;
    const int l = tid & 63;
    const int lane16 = l & 15;
    const int quad = l >> 4;
    const size_t rowbase = (size_t)b * T_SEQ + (size_t)c * CHUNK_L;

    {
        const int dk0 = (tid >> 4) * 8;
        const int jb = (tid & 15) * 4;
        half8 r0 = *(const half8*)&Kf[(rowbase + jb + 0) * HIDDEN + h * DKV + dk0];
        half8 r1 = *(const half8*)&Kf[(rowbase + jb + 1) * HIDDEN + h * DKV + dk0];
        half8 r2 = *(const half8*)&Kf[(rowbase + jb + 2) * HIDDEN + h * DKV + dk0];
        half8 r3 = *(const half8*)&Kf[(rowbase + jb + 3) * HIDDEN + h * DKV + dk0];
#pragma unroll
        for (int dk = 0; dk < 8; ++dk) {
            HBits a0, a1, a2, a3;
            a0.h = r0[dk]; a1.h = r1[dk]; a2.h = r2[dk]; a3.h = r3[dk];
            unsigned int lo = ((unsigned int)a1.u << 16) | a0.u;
            unsigned int hi = ((unsigned int)a3.u << 16) | a2.u;
            *(unsigned int*)&kt[(dk0 + dk) * 72 + jb] = lo;
            *(unsigned int*)&kt[(dk0 + dk) * 72 + jb + 2] = hi;
        }
    }
    __syncthreads();

    const int m0 = (w >> 1) * 64;
    const int n0 = (w & 1) * 64;
    floatx4 acc[4][4];
#pragma unroll
    for (int i = 0; i < 4; ++i)
#pragma unroll
        for (int j = 0; j < 4; ++j)
            acc[i][j] = (floatx4){0.f, 0.f, 0.f, 0.f};

#pragma unroll
    for (int s = 0; s < 2; ++s) {
        half8 a[4], bb[4];
#pragma unroll
        for (int mt = 0; mt < 4; ++mt) {
            int dv = m0 + mt * 16 + lane16;
            a[mt] = *(const half8*)&VT[((size_t)bh * DKV + dv) * T_SEQ + c * CHUNK_L + s * 32 + quad * 8];
        }
#pragma unroll
        for (int nt = 0; nt < 4; ++nt)
            bb[nt] = *(const half8*)&kt[(n0 + nt * 16 + lane16) * 72 + s * 32 + quad * 8];
#pragma unroll
        for (int mt = 0; mt < 4; ++mt)
#pragma unroll
            for (int nt = 0; nt < 4; ++nt)
                acc[mt][nt] = __builtin_amdgcn_mfma_f32_16x16x32_f16(a[mt], bb[nt], acc[mt][nt], 0, 0, 0);
    }

    _Float16* Gp = G16 + ((size_t)bh * NCH + c) * (DKV * DKV);
#pragma unroll
    for (int mt = 0; mt < 4; ++mt)
#pragma unroll
        for (int nt = 0; nt < 4; ++nt)
#pragma unroll
            for (int r = 0; r < 4; ++r)
                Gp[(size_t)(m0 + mt * 16 + quad * 4 + r) * DKV + n0 + nt * 16 + lane16] =
                    (_Float16)acc[mt][nt][r];
}

// ---------------------------------------------------------------------------
// Exclusive prefix over chunks; G16 fp16 in -> Gh fp16 out (scaled SCALE_P),
// running sum kept in fp32.
// ---------------------------------------------------------------------------
__global__ void prefix_kernel(const _Float16* __restrict__ G16, _Float16* __restrict__ Gh)
{
    int idx = blockIdx.x * 256 + threadIdx.x;   // 16 * 16384
    int bh = idx >> 14;
    int e = idx & 16383;
    const _Float16* p = G16 + (size_t)bh * NCH * 16384 + e;
    _Float16* q = Gh + (size_t)bh * NCH * 16384 + e;
    float run = 0.f;
#pragma unroll
    for (int c = 0; c < NCH; ++c) {
        q[(size_t)c * 16384] = (_Float16)(run * SCALE_P);
        run += (float)p[(size_t)c * 16384];
    }
}

// ---------------------------------------------------------------------------
// Attention per chunk, MFMA.
// ---------------------------------------------------------------------------
#define PSLD 40
__global__ __launch_bounds__(256) void attn_mfma(const _Float16* __restrict__ Qf,
                                                 const _Float16* __restrict__ Kf,
                                                 const _Float16* __restrict__ VT,
                                                 const _Float16* __restrict__ Gh,
                                                 _Float16* __restrict__ O)
{
    __shared__ _Float16 ps[2 * 64 * PSLD];
    const int c = blockIdx.x;
    const int bh = blockIdx.y;
    const int b = bh >> 3, h = bh & 7;
    const int tid = threadIdx.x;
    const int w = tid >> 6;
    const int l = tid & 63;
    const int lane16 = l & 15;
    const int quad = l >> 4;
    const size_t rowbase = (size_t)b * T_SEQ + (size_t)c * CHUNK_L;

    {
        const int m0 = (w >> 1) * 32;
        const int n0 = (w & 1) * 32;
        floatx4 aq[2][2];
#pragma unroll
        for (int i = 0; i < 2; ++i)
#pragma unroll
            for (int j = 0; j < 2; ++j)
                aq[i][j] = (floatx4){0.f, 0.f, 0.f, 0.f};
#pragma unroll
        for (int s = 0; s < 4; ++s) {
            half8 a[2], bb[2];
#pragma unroll
            for (int mt = 0; mt < 2; ++mt)
                a[mt] = *(const half8*)&Qf[(rowbase + m0 + mt * 16 + lane16) * HIDDEN +
                                           h * DKV + s * 32 + quad * 8];
#pragma unroll
            for (int nt = 0; nt < 2; ++nt)
                bb[nt] = *(const half8*)&Kf[(rowbase + n0 + nt * 16 + lane16) * HIDDEN +
                                            h * DKV + s * 32 + quad * 8];
#pragma unroll
            for (int mt = 0; mt < 2; ++mt)
#pragma unroll
                for (int nt = 0; nt < 2; ++nt)
                    aq[mt][nt] = __builtin_amdgcn_mfma_f32_16x16x32_f16(a[mt], bb[nt], aq[mt][nt], 0, 0, 0);
        }
#pragma unroll
        for (int mt = 0; mt < 2; ++mt)
#pragma unroll
            for (int nt = 0; nt < 2; ++nt) {
                int j = n0 + nt * 16 + lane16;
#pragma unroll
                for (int r = 0; r < 4; ++r) {
                    int i = m0 + mt * 16 + quad * 4 + r;
                    float v = (j <= i) ? aq[mt][nt][r] * SCALE_P : 0.f;
                    ps[(j >> 5) * 64 * PSLD + i * PSLD + (j & 31)] = (_Float16)v;
                }
            }
    }
    __syncthreads();

    const int n0o = w * 32;
    floatx4 accO[4][2];
#pragma unroll
    for (int i = 0; i < 4; ++i)
#pragma unroll
        for (int j = 0; j < 2; ++j)
            accO[i][j] = (floatx4){0.f, 0.f, 0.f, 0.f};

#pragma unroll
    for (int s = 0; s < 2; ++s) {
        half8 a[4], bb[2];
#pragma unroll
        for (int mt = 0; mt < 4; ++mt)
            a[mt] = *(const half8*)&ps[s * 64 * PSLD + (mt * 16 + lane16) * PSLD + quad * 8];
#pragma unroll
        for (int nt = 0; nt < 2; ++nt) {
            int dv = n0o + nt * 16 + lane16;
            bb[nt] = *(const half8*)&VT[((size_t)bh * DKV + dv) * T_SEQ + c * CHUNK_L + s * 32 + quad * 8];
        }
#pragma unroll
        for (int mt = 0; mt < 4; ++mt)
#pragma unroll
            for (int nt = 0; nt < 2; ++nt)
                accO[mt][nt] = __builtin_amdgcn_mfma_f32_16x16x32_f16(a[mt], bb[nt], accO[mt][nt], 0, 0, 0);
    }

    const _Float16* gh = Gh + ((size_t)bh * NCH + c) * (DKV * DKV);
#pragma unroll
    for (int s = 0; s < 4; ++s) {
        half8 a[4], bb[2];
#pragma unroll
        for (int mt = 0; mt < 4; ++mt)
            a[mt] = *(const half8*)&Qf[(rowbase + mt * 16 + lane16) * HIDDEN +
                                       h * DKV + s * 32 + quad * 8];
#pragma unroll
        for (int nt = 0; nt < 2; ++nt) {
            int dv = n0o + nt * 16 + lane16;
            bb[nt] = *(const half8*)&gh[(size_t)dv * DKV + s * 32 + quad * 8];
        }
#pragma unroll
        for (int mt = 0; mt < 4; ++mt)
#pragma unroll
            for (int nt = 0; nt < 2; ++nt)
                accO[mt][nt] = __builtin_amdgcn_mfma_f32_16x16x32_f16(a[mt], bb[nt], accO[mt][nt], 0, 0, 0);
    }

#pragma unroll
    for (int mt = 0; mt < 4; ++mt)
#pragma unroll
        for (int nt = 0; nt < 2; ++nt)
#pragma unroll
            for (int r = 0; r < 4; ++r)
                O[(rowbase + mt * 16 + quad * 4 + r) * HIDDEN + h * DKV + n0o + nt * 16 + lane16] =
                    (_Float16)(accO[mt][nt][r] * OEPS);
}

// ---------------------------------------------------------------------------
// Workspace map (192 MiB, phase-aliased):
//   [0,16)    h16 (P0-P1) -> qf16 (P3-P6)
//   [16,32)   weights (whole run)
//   [32,80)   qkvlin (P1-P2); kf16 at [48,64) (P3-P6)
//   [64,96)   Gh (P5-P6)
//   [80,96)   qc16 (P2-P3)
//   [96,112)  kc16 (P2-P3) -> O16 (P6-P7)
//   [112,128) vT (P2-P6)
//   [128,160) G16 fp16 (P4-P5)
// ---------------------------------------------------------------------------
extern "C" void kernel_launch(void* const* d_in, const int* in_sizes, int n_in,
                              void* d_out, int out_size, void* d_ws, size_t ws_size,
                              hipStream_t stream)
{
    (void)in_sizes; (void)n_in; (void)out_size; (void)ws_size;
    const float* hs = (const float*)d_in[0];
    const float* wq = (const float*)d_in[1];
    const float* wk = (const float*)d_in[2];
    const float* wv = (const float*)d_in[3];
    const float* wo = (const float*)d_in[4];
    const float* cq = (const float*)d_in[5];
    const float* ck = (const float*)d_in[6];
    const float* cv = (const float*)d_in[7];
    const float* fmq_w1 = (const float*)d_in[8];
    const float* fmq_b1 = (const float*)d_in[9];
    const float* fmq_w2 = (const float*)d_in[10];
    const float* fmq_b2 = (const float*)d_in[11];
    const float* fmk_w1 = (const float*)d_in[12];
    const float* fmk_b1 = (const float*)d_in[13];
    const float* fmk_w2 = (const float*)d_in[14];
    const float* fmk_b2 = (const float*)d_in[15];
    float* out = (float*)d_out;
    char* ws = (char*)d_ws;

    const size_t MB = 1024 * 1024;
    _Float16* h16     = (_Float16*)(ws + 0);
    _Float16* wqkv16  = (_Float16*)(ws + 16 * MB);         // 3072x1024
    _Float16* wo16    = wqkv16 + (3 << 20);
    _Float16* fmw     = wqkv16 + (4 << 20);                // 4 x 16384
    _Float16* qkvlin  = (_Float16*)(ws + 32 * MB);         // [8192][3072]
    _Float16* qf16    = (_Float16*)(ws + 0);
    _Float16* kf16    = (_Float16*)(ws + 48 * MB);
    _Float16* Gh      = (_Float16*)(ws + 64 * MB);         // 32 MB
    _Float16* qc16    = (_Float16*)(ws + 80 * MB);
    _Float16* kc16    = (_Float16*)(ws + 96 * MB);
    _Float16* O16     = (_Float16*)(ws + 96 * MB);
    _Float16* vT      = (_Float16*)(ws + 112 * MB);
    _Float16* G16     = (_Float16*)(ws + 128 * MB);        // 32 MB fp16

    // ---- P0: casts (2 launches) ----
    cast_f32_f16<<<4096, 256, 0, stream>>>(hs, h16, BT * HIDDEN / 8);
    cast8_f32_f16<<<dim3(512, 8), 256, 0, stream>>>(
        wq, wk, wv, wo, fmq_w1, fmq_w2, fmk_w1, fmk_w2,
        wqkv16, wqkv16 + (1 << 20), wqkv16 + (2 << 20), wo16,
        fmw, fmw + 16384, fmw + 2 * 16384, fmw + 3 * 16384,
        HIDDEN * HIDDEN / 8, DKV * DKV / 8);

    // ---- P1: fused QKV projection (N = 3072), 128x128 tiles, BK=64 ----
    dim3 gqkv(3 * HIDDEN / 128, BT / 128);   // (24, 64) = 1536 blocks
    gemm_nt_f16_h16<<<gqkv, 256, 0, stream>>>(h16, wqkv16, qkvlin, BT, 3 * HIDDEN, HIDDEN);

    // ---- P2: conv + silu (q,k,v in ONE launch) ----
    conv_silu_all<<<dim3(2048, 3), 256, 0, stream>>>(
        qkvlin, 3 * HIDDEN, cq, ck, cv, qc16, kc16, vT);

    // ---- P3: feature maps (q,k fused) ----
    dim3 fg(BT / 64, NHEAD, 2);
    fm_mfma2<<<fg, 256, 0, stream>>>(qc16, kc16, fmw, fmq_b1, fmq_b2, fmk_b1, fmk_b2, qf16, kf16);

    // ---- P4-P6: chunked linear attention ----
    dim3 ag(NCH, BATCH * NHEAD);
    ktv_mfma<<<ag, 256, 0, stream>>>(kf16, vT, G16);
    prefix_kernel<<<(16 * 16384) / 256, 256, 0, stream>>>(G16, Gh);
    attn_mfma<<<ag, 256, 0, stream>>>(qf16, kf16, vT, Gh, O16);

    // ---- P7: output projection (undo SCALE_O), BK=64 ----
    dim3 gg(HIDDEN / 128, BT / 128);
    gemm_nt_f16_f32<<<gg, 256, 0, stream>>>(O16, wo16, out, BT, HIDDEN, HIDDEN, 1.0f / SCALE_O);
}